// Round 9
// baseline (855.335 us; speedup 1.0000x reference)
//
#include <hip/hip_runtime.h>
#include <cstdint>
#include <cstddef>

// Problem constants (fixed by reference)
#define N_ROWS  32768
#define DIMS    512
#define K_CODES 8192

typedef short    bf16x8 __attribute__((ext_vector_type(8)));
typedef float    f32x4  __attribute__((ext_vector_type(4)));

__device__ __forceinline__ unsigned short cvt_bf16_rne(float f) {
  union { float f; unsigned u; } c; c.f = f;
  unsigned r = c.u + 0x7FFFu + ((c.u >> 16) & 1u);
  return (unsigned short)(r >> 16);
}

// ===========================================================================
// Oracle model (validated round 4, absmax 4.8e-7):
//  - norms: numpy pairwise fp32; elementwise sqrt/max/div correctly rounded
//  - big dot: BLAS sgemm = one strictly d-ascending fp32 FMA chain
//  - d = fl(fl(xn2+wn2) - 2*dot); stable argsort ties -> lower index
// ===========================================================================

__device__ __forceinline__ float np_pairwise_sumsq_512(const float* buf, int l) {
  int blk = l >> 4, jv = (l >> 2) & 3, ln = l & 3;
  int cb = blk * 128 + jv * 4 + ln;
  float v = buf[cb];
  float r = __fmul_rn(v, v);
  #pragma unroll
  for (int i = 1; i < 8; ++i) {
    float t = buf[cb + 16 * i];
    r = __fadd_rn(r, __fmul_rn(t, t));
  }
  r = __fadd_rn(r, __shfl_xor(r, 4, 64));
  r = __fadd_rn(r, __shfl_xor(r, 8, 64));
  r = __fadd_rn(r, __shfl_xor(r, 1, 64));
  r = __fadd_rn(r, __shfl_xor(r, 2, 64));
  r = __fadd_rn(r, __shfl_xor(r, 16, 64));
  r = __fadd_rn(r, __shfl_xor(r, 32, 64));
  return r;
}

// ---------------------------------------------------------------------------
// prep_x: per-row inverse fp32 norm (approx path: candidates only)
// ---------------------------------------------------------------------------
__global__ __launch_bounds__(256) void prep_x_kernel(
    const float* __restrict__ x, float* __restrict__ xninv) {
  int row = blockIdx.x * 4 + (threadIdx.x >> 6);
  int l = threadIdx.x & 63;
  const float* xr = x + (size_t)row * DIMS + l * 8;
  float4 a = *(const float4*)xr;
  float4 b = *(const float4*)(xr + 4);
  float s = a.x*a.x + a.y*a.y + a.z*a.z + a.w*a.w
          + b.x*b.x + b.y*b.y + b.z*b.z + b.w*b.w;
  #pragma unroll
  for (int off = 1; off < 64; off <<= 1) s += __shfl_xor(s, off, 64);
  float den = fmaxf(sqrtf(s), 1e-12f);
  if (l == 0) xninv[row] = 1.0f / den;
}

// ---------------------------------------------------------------------------
// prep_w_np: numpy-faithful fp32 norm denominator + wn2 (of normalized) +
// bf16 normalized copy for the MFMA candidate pass. wn itself is NOT
// materialized: refine recomputes __fdiv_rn(raw, den) bit-identically.
// ---------------------------------------------------------------------------
__global__ __launch_bounds__(256) void prep_w_np_kernel(
    const float* __restrict__ emb, float* __restrict__ den_w,
    float* __restrict__ wnorm2, unsigned short* __restrict__ wnh) {
  __shared__ float buf[4][512];
  int w = threadIdx.x >> 6, l = threadIdx.x & 63;
  int row = blockIdx.x * 4 + w;
  const float* wr = emb + (size_t)row * DIMS + l * 8;
  float4 a = *(const float4*)wr;
  float4 b = *(const float4*)(wr + 4);
  *(float4*)&buf[w][l * 8]     = a;
  *(float4*)&buf[w][l * 8 + 4] = b;
  __syncthreads();
  float S = np_pairwise_sumsq_512(buf[w], l);
  float den = fmaxf(__fsqrt_rn(S), 1e-12f);
  float nv[8];
  nv[0] = __fdiv_rn(a.x, den); nv[1] = __fdiv_rn(a.y, den);
  nv[2] = __fdiv_rn(a.z, den); nv[3] = __fdiv_rn(a.w, den);
  nv[4] = __fdiv_rn(b.x, den); nv[5] = __fdiv_rn(b.y, den);
  nv[6] = __fdiv_rn(b.z, den); nv[7] = __fdiv_rn(b.w, den);
  __syncthreads();   // chains done reading raw w before overwrite
  *(float4*)&buf[w][l * 8]     = float4{nv[0], nv[1], nv[2], nv[3]};
  *(float4*)&buf[w][l * 8 + 4] = float4{nv[4], nv[5], nv[6], nv[7]};
  {
    unsigned hv[4];
    #pragma unroll
    for (int j = 0; j < 4; ++j) {
      unsigned lo = cvt_bf16_rne(nv[2*j]);
      unsigned hi = cvt_bf16_rne(nv[2*j + 1]);
      hv[j] = lo | (hi << 16);
    }
    *(uint4*)(wnh + (size_t)row * DIMS + l * 8) =
        uint4{hv[0], hv[1], hv[2], hv[3]};
  }
  __syncthreads();
  float S2 = np_pairwise_sumsq_512(buf[w], l);
  if (l == 0) { wnorm2[row] = S2; den_w[row] = den; }
}

// ===========================================================================
// MFMA candidate path v11:
//  - v10 post-mortem: allocator targeted max occupancy (VGPR budget 64) and
//    spilled afrag AGAIN (WRITE 133 MB == 252 B/thread; 8 KB/thread scratch
//    re-reads per t-loop = 4.3 GB/dispatch through L2). launch_bounds /
//    waves_per_eu do NOT pin the budget — the heuristic overrides.
//  - v11: pin afrag into AGPRs via empty `asm volatile("" : "+a"(frag))`.
//    gfx950 MFMA reads A/B operands directly from AGPRs (ISA sec10), and the
//    allocator never spills asm-pinned AGPRs. Arch-VGPR need drops to ~60
//    (fits even a 64-reg budget); afrag lives in 64 AGPRs. Zero scratch.
//  - waves_per_eu attribute REMOVED (it would cap combined budget at 128
//    and re-force the spill).
//  - everything else identical to v10: 8 waves x 16 rows, XCC-pinned 2 MB
//    B-split (FETCH 204 MB proved L2 residency), staged-B pipeline,
//    packed-key top-8 (4 thr/row scan, 4-partial merge).
// ===========================================================================
#define MT_ROWS 128
#define MT_TILES 32          // 32 tiles x 64 cols = 2048-col split
#define NSPLIT 4
#define SPLIT_COLS 2048
#define NROWGRP (N_ROWS / MT_ROWS)   // 256 per split queue
#define BSTR_B 272          // B LDS row stride in BYTES (128 bf16 + 8 pad)
#define DSTR   33           // dump row stride in dwords
#define QSTRIDE 32          // qctr slot stride in dwords (128 B)

__global__
__attribute__((amdgpu_flat_work_group_size(512, 512)))
void mfma_topk_kernel(
    const float* __restrict__ x, const unsigned short* __restrict__ wnh,
    const float* __restrict__ xninv, unsigned* __restrict__ candk,
    unsigned* __restrict__ qctr) {
  __shared__ unsigned short Bs[64 * (BSTR_B / 2)];   // 17408 B
  unsigned* dump = (unsigned*)Bs;                    // 128 x 33 u32 = 16.9 KB
  __shared__ int s_rg, s_sp;

  const int tid = threadIdx.x;       // 0..511
  const int lane = tid & 63;
  const int wv = tid >> 6;           // 0..7
  const int l15 = lane & 15;
  const int lq = lane >> 4;

  // ---- claim exactly one (rowgrp, split) item, pinned to physical die ----
  if (tid == 0) {
    unsigned xcc;
    asm("s_getreg_b32 %0, hwreg(HW_REG_XCC_ID)" : "=s"(xcc));
    const int mysplit = (int)(xcc & 3);
    int rg = -1, sp = 0;
    #pragma unroll 1
    for (int i = 0; i < NSPLIT; ++i) {
      int s = (mysplit + i) & (NSPLIT - 1);
      unsigned r = atomicAdd(&qctr[s * QSTRIDE], 1u);
      if (r < (unsigned)NROWGRP) { rg = (int)r; sp = s; break; }
    }
    s_rg = rg; s_sp = sp;
  }
  __syncthreads();
  const int rowgrp = s_rg;
  const int split = s_sp;
  if (rowgrp < 0) return;           // cannot happen (grid == items); safety
  const int row0 = rowgrp * MT_ROWS;
  const int col0 = split * SPLIT_COLS;

  const int scol = tid >> 3;        // staging col 0..63
  const int spart = tid & 7;        // staging k-part (32 B each)

  // ---- A fragments: one 16-row slice per wave, pinned into AGPRs ----
  bf16x8 afrag[16];
  {
    int row = row0 + wv * 16 + l15;
    float sc = xninv[row];
    const float* xp = x + (size_t)row * DIMS + lq * 8;
    #pragma unroll
    for (int ks = 0; ks < 16; ++ks) {
      float4 a = *(const float4*)(xp + ks * 32);
      float4 b = *(const float4*)(xp + ks * 32 + 4);
      bf16x8 f;
      f[0] = (short)cvt_bf16_rne(a.x * sc); f[1] = (short)cvt_bf16_rne(a.y * sc);
      f[2] = (short)cvt_bf16_rne(a.z * sc); f[3] = (short)cvt_bf16_rne(a.w * sc);
      f[4] = (short)cvt_bf16_rne(b.x * sc); f[5] = (short)cvt_bf16_rne(b.y * sc);
      f[6] = (short)cvt_bf16_rne(b.z * sc); f[7] = (short)cvt_bf16_rne(b.w * sc);
      afrag[ks] = f;
      // Pin into the AGPR half of the unified file: the allocator will not
      // spill asm-pinned AGPRs, and gfx950 MFMA reads A operands from AGPR.
      asm volatile("" : "+a"(afrag[ks]));
    }
  }

  unsigned m[8];
  #pragma unroll
  for (int j = 0; j < 8; ++j) m[j] = 0u;

  // prefetch (t=0, c=0): 32 B per thread
  uint4 s0, s1;
  {
    const char* p = (const char*)wnh
        + ((size_t)(col0 + scol) * DIMS) * 2 + spart * 32;
    s0 = *(const uint4*)(p);
    s1 = *(const uint4*)(p + 16);
  }

  for (int t = 0; t < MT_TILES; ++t) {
    f32x4 acc[4];
    #pragma unroll
    for (int cs = 0; cs < 4; ++cs)
      acc[cs] = f32x4{0.f, 0.f, 0.f, 0.f};

    #pragma unroll             // FULL unroll: afrag indices stay compile-time
    for (int c = 0; c < 4; ++c) {
      __syncthreads();              // Bs consumers (prev MFMA / scan) done
      char* dst = (char*)Bs + scol * BSTR_B + spart * 32;
      *(uint4*)(dst)      = s0;
      *(uint4*)(dst + 16) = s1;
      // prefetch next chunk (overlaps MFMAs + barriers)
      int nt = t + ((c + 1) >> 2);
      int nc = (c + 1) & 3;
      if (nt < MT_TILES) {
        const char* p = (const char*)wnh
            + ((size_t)(col0 + nt * 64 + scol) * DIMS) * 2
            + nc * 256 + spart * 32;
        s0 = *(const uint4*)(p);
        s1 = *(const uint4*)(p + 16);
      }
      __syncthreads();
      #pragma unroll
      for (int kk = 0; kk < 4; ++kk) {
        const int ks = c * 4 + kk;
        bf16x8 bfr[4];
        #pragma unroll
        for (int cs = 0; cs < 4; ++cs)
          bfr[cs] = *(const bf16x8*)((const char*)Bs
                      + (cs * 16 + l15) * BSTR_B + kk * 64 + lq * 16);
        #pragma unroll
        for (int cs = 0; cs < 4; ++cs)
          acc[cs] = __builtin_amdgcn_mfma_f32_16x16x32_bf16(
              afrag[ks], bfr[cs], acc[cs], 0, 0, 0);
      }
    }
    __syncthreads();                // mfma B reads done; Bs reusable as dump

    // mini-reduce: per (row, col-residue-class) top-2-of-4 packed keys
    #pragma unroll
    for (int rg2 = 0; rg2 < 4; ++rg2) {
      unsigned kkey[4];
      #pragma unroll
      for (int cs = 0; cs < 4; ++cs) {
        float v = acc[cs][rg2];
        union { float f; unsigned u; } cu;
        cu.f = fmaf(v, 0.5f, 2.5f);
        kkey[cs] = ((cu.u << 9) & 0xFFFFF000u)
                 | (unsigned)(t * 64 + cs * 16 + l15);
      }
      unsigned h1 = max(kkey[0], kkey[1]), lo1 = min(kkey[0], kkey[1]);
      unsigned h2 = max(kkey[2], kkey[3]), lo2 = min(kkey[2], kkey[3]);
      unsigned m1 = max(h1, h2);
      unsigned m2 = max(min(h1, h2), max(lo1, lo2));
      int rowl = wv * 16 + lq * 4 + rg2;
      dump[rowl * DSTR + l15 * 2 + 0] = m1;
      dump[rowl * DSTR + l15 * 2 + 1] = m2;
    }
    __syncthreads();

    // streaming top-8: 4 threads per row, 8 queue entries each
    {
      int srow = tid & 127;
      int qb = (tid >> 7) * 8;
      #pragma unroll
      for (int q = 0; q < 8; ++q) {
        unsigned cv = dump[srow * DSTR + qb + q];
        #pragma unroll
        for (int j = 0; j < 8; ++j) {
          unsigned hi = max(m[j], cv), lo = min(m[j], cv);
          m[j] = hi; cv = lo;
        }
      }
    }
    // loop-top barrier protects Bs against next tile's staging write
  }

  // merge the four partial top-8s per row, store
  __syncthreads();
  {
    int g = tid >> 7;          // 0..3
    int srow = tid & 127;
    if (g > 0) {
      #pragma unroll
      for (int j = 0; j < 8; ++j) dump[srow * DSTR + (g - 1) * 8 + j] = m[j];
    }
    __syncthreads();
    if (g == 0) {
      #pragma unroll 1
      for (int e = 0; e < 24; ++e) {
        unsigned cv = dump[srow * DSTR + e];
        #pragma unroll
        for (int jj = 0; jj < 8; ++jj) {
          unsigned hi = max(m[jj], cv), lo = min(m[jj], cv);
          m[jj] = hi; cv = lo;
        }
      }
      unsigned* o = candk + (size_t)(row0 + srow) * 32 + split * 8;
      #pragma unroll
      for (int j = 0; j < 8; ++j) o[j] = m[j];
    }
  }
}

// ---------------------------------------------------------------------------
// refine v8 (unchanged): 4-at-a-time staging, pipelined gathers, atomic-free
// loss (per-row partials + 1-block finalize).
// ---------------------------------------------------------------------------
#define WSTR 516

__global__ __launch_bounds__(256, 3) void refine_mfma_kernel(
    const float* __restrict__ x, const float* __restrict__ emb,
    const float* __restrict__ den_w, const float* __restrict__ wnorm2,
    const unsigned* __restrict__ candk,
    float* __restrict__ out, double* __restrict__ lossparts) {
  __shared__ float xbuf[4][512];
  __shared__ float wbuf4[4][4 * WSTR];
  int w = threadIdx.x >> 6, l = threadIdx.x & 63;
  int row = blockIdx.x * 4 + w;

  const float* xr = x + (size_t)row * DIMS + l * 8;
  float4 x0 = *(const float4*)xr;
  float4 x1 = *(const float4*)(xr + 4);
  *(float4*)&xbuf[w][l * 8]     = x0;
  *(float4*)&xbuf[w][l * 8 + 4] = x1;
  __syncthreads();
  float Sx = np_pairwise_sumsq_512(xbuf[w], l);
  float denx = fmaxf(__fsqrt_rn(Sx), 1e-12f);
  float xn[8];
  xn[0] = __fdiv_rn(x0.x, denx); xn[1] = __fdiv_rn(x0.y, denx);
  xn[2] = __fdiv_rn(x0.z, denx); xn[3] = __fdiv_rn(x0.w, denx);
  xn[4] = __fdiv_rn(x1.x, denx); xn[5] = __fdiv_rn(x1.y, denx);
  xn[6] = __fdiv_rn(x1.z, denx); xn[7] = __fdiv_rn(x1.w, denx);
  __syncthreads();
  *(float4*)&xbuf[w][l * 8]     = float4{xn[0], xn[1], xn[2], xn[3]};
  *(float4*)&xbuf[w][l * 8 + 4] = float4{xn[4], xn[5], xn[6], xn[7]};
  __syncthreads();
  float xn2 = np_pairwise_sumsq_512(xbuf[w], l);

  // decode candidates: 4 splits x 8 keys, col-in-split is 11 bits
  unsigned val = 0u; int col = 0x7fffffff;
  if (l < 32) {
    unsigned key = candk[(size_t)row * 32 + l];
    val = key >> 12;
    col = (l >> 3) * SPLIT_COLS + (int)(key & 0xFFFu);
  }

  int k8[8];
  #pragma unroll
  for (int it = 0; it < 8; ++it) {
    unsigned mv = val; int mk = col;
    #pragma unroll
    for (int off = 1; off < 64; off <<= 1) {
      unsigned ov = (unsigned)__shfl_xor((int)mv, off, 64);
      int ok = __shfl_xor(mk, off, 64);
      bool take = (ov > mv) || (ov == mv && ok < mk);
      mv = take ? ov : mv; mk = take ? ok : mk;
    }
    k8[it] = mk;
    if (col == mk) val = 0u;
  }

  // ---- software-pipelined gather + 2 groups of 4 staged candidates ----
  float4 ga[4], gb[4];
  #pragma unroll
  for (int c = 0; c < 4; ++c) {
    const float* wr = emb + (size_t)k8[c] * DIMS + l * 8;
    ga[c] = *(const float4*)wr;
    gb[c] = *(const float4*)(wr + 4);
  }

  float d8[8];
  #pragma unroll
  for (int g = 0; g < 2; ++g) {
    // stage group g: fdiv (bit-identical) + LDS store
    #pragma unroll
    for (int c = 0; c < 4; ++c) {
      float dk = den_w[k8[g * 4 + c]];
      *(float4*)&wbuf4[w][c * WSTR + l * 8] =
          float4{__fdiv_rn(ga[c].x, dk), __fdiv_rn(ga[c].y, dk),
                 __fdiv_rn(ga[c].z, dk), __fdiv_rn(ga[c].w, dk)};
      *(float4*)&wbuf4[w][c * WSTR + l * 8 + 4] =
          float4{__fdiv_rn(gb[c].x, dk), __fdiv_rn(gb[c].y, dk),
                 __fdiv_rn(gb[c].z, dk), __fdiv_rn(gb[c].w, dk)};
    }
    // prefetch group 1 rows while group 0's chain runs (T14)
    if (g == 0) {
      #pragma unroll
      for (int c = 0; c < 4; ++c) {
        const float* wr = emb + (size_t)k8[4 + c] * DIMS + l * 8;
        ga[c] = *(const float4*)wr;
        gb[c] = *(const float4*)(wr + 4);
      }
    }
    __syncthreads();

    // exact sgemm-chain dots: lane computes candidate g*4 + (l&3)
    {
      int j = l & 3;
      const float* xp = xbuf[w];
      const float* wp = &wbuf4[w][j * WSTR];
      float t = 0.f;
      #pragma unroll 8
      for (int d = 0; d < 512; ++d) t = fmaf(xp[d], wp[d], t);
      #pragma unroll
      for (int c = 0; c < 4; ++c) {
        float dot = __shfl(t, c, 64);
        float s = __fadd_rn(xn2, wnorm2[k8[g * 4 + c]]);
        d8[g * 4 + c] = __fadd_rn(s, -(2.0f * dot));
      }
    }
    __syncthreads();   // wbuf4 consumed before group 1 overwrites
  }

  {
    float bd[3]; int bk[3];
    #pragma unroll
    for (int s = 0; s < 3; ++s) {
      float mv = INFINITY; int mk = 0x7fffffff;
      #pragma unroll
      for (int it = 0; it < 8; ++it) {
        bool take = (d8[it] < mv) || (d8[it] == mv && k8[it] < mk);
        mv = take ? d8[it] : mv; mk = take ? k8[it] : mk;
      }
      bd[s] = mv; bk[s] = mk;
      #pragma unroll
      for (int it = 0; it < 8; ++it)
        if (k8[it] == mk) d8[it] = INFINITY;
    }

    double i0 = 1.0 / (double)bd[0], i1 = 1.0 / (double)bd[1],
           i2 = 1.0 / (double)bd[2];
    double tot = (i0 + i1) + i2;
    double w0q = i0 / tot, w1q = i1 / tot, w2q = i2 / tot;

    if (l == 0) {
      float* oi = out + (size_t)N_ROWS * DIMS + 1 + (size_t)row * 3;
      oi[0] = (float)bk[0]; oi[1] = (float)bk[1]; oi[2] = (float)bk[2];
    }

    const float* e0 = emb + (size_t)bk[0] * DIMS + l * 8;
    const float* e1 = emb + (size_t)bk[1] * DIMS + l * 8;
    const float* e2 = emb + (size_t)bk[2] * DIMS + l * 8;
    float4 ea0 = *(const float4*)e0, eb0 = *(const float4*)(e0 + 4);
    float4 ea1 = *(const float4*)e1, eb1 = *(const float4*)(e1 + 4);
    float4 ea2 = *(const float4*)e2, eb2 = *(const float4*)(e2 + 4);
    double xs[8];
    xs[0] = x0.x; xs[1] = x0.y; xs[2] = x0.z; xs[3] = x0.w;
    xs[4] = x1.x; xs[5] = x1.y; xs[6] = x1.z; xs[7] = x1.w;
    double q[8];
    q[0] = w0q*(double)ea0.x + w1q*(double)ea1.x + w2q*(double)ea2.x;
    q[1] = w0q*(double)ea0.y + w1q*(double)ea1.y + w2q*(double)ea2.y;
    q[2] = w0q*(double)ea0.z + w1q*(double)ea1.z + w2q*(double)ea2.z;
    q[3] = w0q*(double)ea0.w + w1q*(double)ea1.w + w2q*(double)ea2.w;
    q[4] = w0q*(double)eb0.x + w1q*(double)eb1.x + w2q*(double)eb2.x;
    q[5] = w0q*(double)eb0.y + w1q*(double)eb1.y + w2q*(double)eb2.y;
    q[6] = w0q*(double)eb0.z + w1q*(double)eb1.z + w2q*(double)eb2.z;
    q[7] = w0q*(double)eb0.w + w1q*(double)eb1.w + w2q*(double)eb2.w;

    double lp = 0.0;
    float o[8];
    #pragma unroll
    for (int jj = 0; jj < 8; ++jj) {
      double diff = q[jj] - xs[jj];
      o[jj] = (float)(xs[jj] + diff);
      lp += diff * diff;
    }
    float* orow = out + (size_t)row * DIMS + l * 8;
    *(float4*)orow       = float4{o[0], o[1], o[2], o[3]};
    *(float4*)(orow + 4) = float4{o[4], o[5], o[6], o[7]};

    #pragma unroll
    for (int off = 1; off < 64; off <<= 1) lp += __shfl_xor(lp, off, 64);
    if (l == 0) lossparts[row] = lp;     // plain store; no atomic
  }
}

__global__ __launch_bounds__(256) void loss_finalize_kernel(
    const double* __restrict__ lossparts, float* __restrict__ out) {
  __shared__ double sred[4];
  int tid = threadIdx.x;
  double s = 0.0;
  for (int i = tid; i < N_ROWS; i += 256) s += lossparts[i];
  #pragma unroll
  for (int off = 1; off < 64; off <<= 1) s += __shfl_xor(s, off, 64);
  if ((tid & 63) == 0) sred[tid >> 6] = s;
  __syncthreads();
  if (tid == 0) {
    double m = (((sred[0] + sred[1]) + sred[2]) + sred[3]) / 16777216.0;
    out[(size_t)N_ROWS * DIMS] = (float)(m + 0.25 * m);
  }
}

// ---------------------------------------------------------------------------
// Workspace layout (~13.04 MB total):
//   wnorm2    [       0 ..   32768)  ||wn||^2 of normalized rows
//   den_w     [   32768 ..   65536)  fp32 norm denominator per codebook row
//   xninv     [   65536 ..  196608)  per-x-row inverse norm
//   wnh       [  196608 .. 8585216)  bf16 normalized codebook (8 MB)
//   candk     [ 8585216 .. 12779520) 32 packed keys/row (4 splits x top-8)
//   lossparts [12779520 .. 13041664) 32768 fp64 per-row partials (256 KB)
//   qctr      [13041664 .. 13042176) 4 queue counters @ 128B stride
// ---------------------------------------------------------------------------
extern "C" void kernel_launch(void* const* d_in, const int* in_sizes, int n_in,
                              void* d_out, int out_size, void* d_ws, size_t ws_size,
                              hipStream_t stream) {
  (void)in_sizes; (void)n_in; (void)out_size; (void)ws_size;
  const float* x   = (const float*)d_in[0];
  const float* emb = (const float*)d_in[1];
  float* out = (float*)d_out;
  char* ws = (char*)d_ws;

  float*          wnorm2    = (float*)(ws);
  float*          den_w     = (float*)(ws + 32768);
  float*          xninv     = (float*)(ws + 65536);
  unsigned short* wnh       = (unsigned short*)(ws + 196608);
  unsigned*       candk     = (unsigned*)(ws + 8585216);
  double*         lossparts = (double*)(ws + 12779520);
  unsigned*       qctr      = (unsigned*)(ws + 13041664);

  prep_w_np_kernel<<<K_CODES / 4, 256, 0, stream>>>(emb, den_w, wnorm2, wnh);
  prep_x_kernel<<<N_ROWS / 4, 256, 0, stream>>>(x, xninv);
  hipMemsetAsync(qctr, 0, 512, stream);
  mfma_topk_kernel<<<NROWGRP * NSPLIT, 512, 0, stream>>>(
      x, wnh, xninv, candk, qctr);
  refine_mfma_kernel<<<N_ROWS / 4, 256, 0, stream>>>(
      x, emb, den_w, wnorm2, candk, out, lossparts);
  loss_finalize_kernel<<<1, 256, 0, stream>>>(lossparts, out);
}

// Round 10
// 718.668 us; speedup vs baseline: 1.1902x; 1.1902x over previous
//
#include <hip/hip_runtime.h>
#include <cstdint>
#include <cstddef>

// Problem constants (fixed by reference)
#define N_ROWS  32768
#define DIMS    512
#define K_CODES 8192

typedef short    bf16x8 __attribute__((ext_vector_type(8)));
typedef float    f32x4  __attribute__((ext_vector_type(4)));

__device__ __forceinline__ unsigned short cvt_bf16_rne(float f) {
  union { float f; unsigned u; } c; c.f = f;
  unsigned r = c.u + 0x7FFFu + ((c.u >> 16) & 1u);
  return (unsigned short)(r >> 16);
}

// ===========================================================================
// Oracle model (validated round 4, absmax 4.8e-7):
//  - norms: numpy pairwise fp32; elementwise sqrt/max/div correctly rounded
//  - big dot: BLAS sgemm = one strictly d-ascending fp32 FMA chain
//  - d = fl(fl(xn2+wn2) - 2*dot); stable argsort ties -> lower index
// ===========================================================================

__device__ __forceinline__ float np_pairwise_sumsq_512(const float* buf, int l) {
  int blk = l >> 4, jv = (l >> 2) & 3, ln = l & 3;
  int cb = blk * 128 + jv * 4 + ln;
  float v = buf[cb];
  float r = __fmul_rn(v, v);
  #pragma unroll
  for (int i = 1; i < 8; ++i) {
    float t = buf[cb + 16 * i];
    r = __fadd_rn(r, __fmul_rn(t, t));
  }
  r = __fadd_rn(r, __shfl_xor(r, 4, 64));
  r = __fadd_rn(r, __shfl_xor(r, 8, 64));
  r = __fadd_rn(r, __shfl_xor(r, 1, 64));
  r = __fadd_rn(r, __shfl_xor(r, 2, 64));
  r = __fadd_rn(r, __shfl_xor(r, 16, 64));
  r = __fadd_rn(r, __shfl_xor(r, 32, 64));
  return r;
}

// ---------------------------------------------------------------------------
// prep_x: per-row inverse fp32 norm (approx path: candidates only)
// ---------------------------------------------------------------------------
__global__ __launch_bounds__(256) void prep_x_kernel(
    const float* __restrict__ x, float* __restrict__ xninv) {
  int row = blockIdx.x * 4 + (threadIdx.x >> 6);
  int l = threadIdx.x & 63;
  const float* xr = x + (size_t)row * DIMS + l * 8;
  float4 a = *(const float4*)xr;
  float4 b = *(const float4*)(xr + 4);
  float s = a.x*a.x + a.y*a.y + a.z*a.z + a.w*a.w
          + b.x*b.x + b.y*b.y + b.z*b.z + b.w*b.w;
  #pragma unroll
  for (int off = 1; off < 64; off <<= 1) s += __shfl_xor(s, off, 64);
  float den = fmaxf(sqrtf(s), 1e-12f);
  if (l == 0) xninv[row] = 1.0f / den;
}

// ---------------------------------------------------------------------------
// prep_w_np: numpy-faithful fp32 norm denominator + wn2 (of normalized) +
// bf16 normalized copy for the MFMA candidate pass. wn itself is NOT
// materialized: refine recomputes __fdiv_rn(raw, den) bit-identically.
// ---------------------------------------------------------------------------
__global__ __launch_bounds__(256) void prep_w_np_kernel(
    const float* __restrict__ emb, float* __restrict__ den_w,
    float* __restrict__ wnorm2, unsigned short* __restrict__ wnh) {
  __shared__ float buf[4][512];
  int w = threadIdx.x >> 6, l = threadIdx.x & 63;
  int row = blockIdx.x * 4 + w;
  const float* wr = emb + (size_t)row * DIMS + l * 8;
  float4 a = *(const float4*)wr;
  float4 b = *(const float4*)(wr + 4);
  *(float4*)&buf[w][l * 8]     = a;
  *(float4*)&buf[w][l * 8 + 4] = b;
  __syncthreads();
  float S = np_pairwise_sumsq_512(buf[w], l);
  float den = fmaxf(__fsqrt_rn(S), 1e-12f);
  float nv[8];
  nv[0] = __fdiv_rn(a.x, den); nv[1] = __fdiv_rn(a.y, den);
  nv[2] = __fdiv_rn(a.z, den); nv[3] = __fdiv_rn(a.w, den);
  nv[4] = __fdiv_rn(b.x, den); nv[5] = __fdiv_rn(b.y, den);
  nv[6] = __fdiv_rn(b.z, den); nv[7] = __fdiv_rn(b.w, den);
  __syncthreads();   // chains done reading raw w before overwrite
  *(float4*)&buf[w][l * 8]     = float4{nv[0], nv[1], nv[2], nv[3]};
  *(float4*)&buf[w][l * 8 + 4] = float4{nv[4], nv[5], nv[6], nv[7]};
  {
    unsigned hv[4];
    #pragma unroll
    for (int j = 0; j < 4; ++j) {
      unsigned lo = cvt_bf16_rne(nv[2*j]);
      unsigned hi = cvt_bf16_rne(nv[2*j + 1]);
      hv[j] = lo | (hi << 16);
    }
    *(uint4*)(wnh + (size_t)row * DIMS + l * 8) =
        uint4{hv[0], hv[1], hv[2], hv[3]};
  }
  __syncthreads();
  float S2 = np_pairwise_sumsq_512(buf[w], l);
  if (l == 0) { wnorm2[row] = S2; den_w[row] = den; }
}

// ===========================================================================
// MFMA candidate path v12:
//  - v11 post-mortem: AGPR pin WORKED (WRITE 133->4.1 MB, zero spill) but
//    dur rose 463->543 us. With clean counters the bottleneck is LDS read
//    BW: 8-wave/16-row geometry gives 1 MFMA per bfr read -> 16.8 GB of
//    ds_read per dispatch (243 us at the 69 TB/s ceiling, ~500 us with the
//    +5cyc/read conflict overhead measured: 8.6e7 conflicts).
//  - v12: revert to 4 waves x 32 rows (2 MFMAs per bfr read -> 8.4 GB LDS)
//    and keep afrag[2][16] pinned in 128 AGPRs (asm "+a") -- the two
//    individually-proven mechanisms combined. ~90 arch VGPR + 128 AGPR =
//    ~218/wave -> 2 waves/SIMD, 2 blocks/CU (same occupancy as v11, half
//    the LDS traffic per MFMA).
//  - XCC-pinned 2 MB B-split kept (FETCH 164-204 MB proves L2 residency).
// ===========================================================================
#define MT_ROWS 128
#define MT_TILES 32          // 32 tiles x 64 cols = 2048-col split
#define NSPLIT 4
#define SPLIT_COLS 2048
#define NROWGRP (N_ROWS / MT_ROWS)   // 256 per split queue
#define BSTR_B 272          // B LDS row stride in BYTES (128 bf16 + 8 pad)
#define DSTR   33           // dump row stride in dwords
#define QSTRIDE 32          // qctr slot stride in dwords (128 B)

__global__
__attribute__((amdgpu_flat_work_group_size(256, 256), amdgpu_waves_per_eu(2, 2)))
void mfma_topk_kernel(
    const float* __restrict__ x, const unsigned short* __restrict__ wnh,
    const float* __restrict__ xninv, unsigned* __restrict__ candk,
    unsigned* __restrict__ qctr) {
  __shared__ unsigned short Bs[64 * (BSTR_B / 2)];   // 17408 B
  unsigned* dump = (unsigned*)Bs;                    // 128 x 33 u32 = 16.9 KB
  __shared__ int s_rg, s_sp;

  const int tid = threadIdx.x;       // 0..255
  const int lane = tid & 63;
  const int wv = tid >> 6;           // 0..3
  const int l15 = lane & 15;
  const int lq = lane >> 4;

  // ---- claim exactly one (rowgrp, split) item, pinned to physical die ----
  if (tid == 0) {
    unsigned xcc;
    asm("s_getreg_b32 %0, hwreg(HW_REG_XCC_ID)" : "=s"(xcc));
    const int mysplit = (int)(xcc & 3);
    int rg = -1, sp = 0;
    #pragma unroll 1
    for (int i = 0; i < NSPLIT; ++i) {
      int s = (mysplit + i) & (NSPLIT - 1);
      unsigned r = atomicAdd(&qctr[s * QSTRIDE], 1u);
      if (r < (unsigned)NROWGRP) { rg = (int)r; sp = s; break; }
    }
    s_rg = rg; s_sp = sp;
  }
  __syncthreads();
  const int rowgrp = s_rg;
  const int split = s_sp;
  if (rowgrp < 0) return;           // cannot happen (grid == items); safety
  const int row0 = rowgrp * MT_ROWS;
  const int col0 = split * SPLIT_COLS;

  const int scol = tid >> 2;        // staging col 0..63
  const int spart = tid & 3;        // staging k-part (64 B each)

  // ---- A fragments: 32 rows per wave (2 slices), pinned into AGPRs ----
  bf16x8 afrag[2][16];
  #pragma unroll
  for (int rs = 0; rs < 2; ++rs) {
    int row = row0 + wv * 32 + rs * 16 + l15;
    float sc = xninv[row];
    const float* xp = x + (size_t)row * DIMS + lq * 8;
    #pragma unroll
    for (int ks = 0; ks < 16; ++ks) {
      float4 a = *(const float4*)(xp + ks * 32);
      float4 b = *(const float4*)(xp + ks * 32 + 4);
      bf16x8 f;
      f[0] = (short)cvt_bf16_rne(a.x * sc); f[1] = (short)cvt_bf16_rne(a.y * sc);
      f[2] = (short)cvt_bf16_rne(a.z * sc); f[3] = (short)cvt_bf16_rne(a.w * sc);
      f[4] = (short)cvt_bf16_rne(b.x * sc); f[5] = (short)cvt_bf16_rne(b.y * sc);
      f[6] = (short)cvt_bf16_rne(b.z * sc); f[7] = (short)cvt_bf16_rne(b.w * sc);
      afrag[rs][ks] = f;
      // Pin into the AGPR half of the unified file (proven v11: allocator
      // will not spill asm-pinned AGPRs; gfx950 MFMA reads A from AGPR).
      asm volatile("" : "+a"(afrag[rs][ks]));
    }
  }

  unsigned m[8];
  #pragma unroll
  for (int j = 0; j < 8; ++j) m[j] = 0u;

  // prefetch (t=0, c=0): 64 B per thread
  uint4 s0, s1, s2, s3;
  {
    const char* p = (const char*)wnh
        + ((size_t)(col0 + scol) * DIMS) * 2 + spart * 64;
    s0 = *(const uint4*)(p);
    s1 = *(const uint4*)(p + 16);
    s2 = *(const uint4*)(p + 32);
    s3 = *(const uint4*)(p + 48);
  }

  for (int t = 0; t < MT_TILES; ++t) {
    f32x4 acc[2][4];
    #pragma unroll
    for (int rs = 0; rs < 2; ++rs)
      #pragma unroll
      for (int cs = 0; cs < 4; ++cs)
        acc[rs][cs] = f32x4{0.f, 0.f, 0.f, 0.f};

    #pragma unroll             // FULL unroll: afrag indices stay compile-time
    for (int c = 0; c < 4; ++c) {
      __syncthreads();              // Bs consumers (prev MFMA / scan) done
      char* dst = (char*)Bs + scol * BSTR_B + spart * 64;
      *(uint4*)(dst)      = s0;
      *(uint4*)(dst + 16) = s1;
      *(uint4*)(dst + 32) = s2;
      *(uint4*)(dst + 48) = s3;
      // prefetch next chunk (overlaps MFMAs + barriers)
      int nt = t + ((c + 1) >> 2);
      int nc = (c + 1) & 3;
      if (nt < MT_TILES) {
        const char* p = (const char*)wnh
            + ((size_t)(col0 + nt * 64 + scol) * DIMS) * 2
            + nc * 256 + spart * 64;
        s0 = *(const uint4*)(p);
        s1 = *(const uint4*)(p + 16);
        s2 = *(const uint4*)(p + 32);
        s3 = *(const uint4*)(p + 48);
      }
      __syncthreads();
      #pragma unroll
      for (int kk = 0; kk < 4; ++kk) {
        const int ks = c * 4 + kk;
        bf16x8 bfr[4];
        #pragma unroll
        for (int cs = 0; cs < 4; ++cs)
          bfr[cs] = *(const bf16x8*)((const char*)Bs
                      + (cs * 16 + l15) * BSTR_B + kk * 64 + lq * 16);
        #pragma unroll
        for (int rs = 0; rs < 2; ++rs)
          #pragma unroll
          for (int cs = 0; cs < 4; ++cs)
            acc[rs][cs] = __builtin_amdgcn_mfma_f32_16x16x32_bf16(
                afrag[rs][ks], bfr[cs], acc[rs][cs], 0, 0, 0);
      }
    }
    __syncthreads();                // mfma B reads done; Bs reusable as dump

    // mini-reduce: per (row, col-residue-class) top-2-of-4 packed keys
    #pragma unroll
    for (int rs = 0; rs < 2; ++rs)
      #pragma unroll
      for (int rg2 = 0; rg2 < 4; ++rg2) {
        unsigned kkey[4];
        #pragma unroll
        for (int cs = 0; cs < 4; ++cs) {
          float v = acc[rs][cs][rg2];
          union { float f; unsigned u; } cu;
          cu.f = fmaf(v, 0.5f, 2.5f);
          kkey[cs] = ((cu.u << 9) & 0xFFFFF000u)
                   | (unsigned)(t * 64 + cs * 16 + l15);
        }
        unsigned h1 = max(kkey[0], kkey[1]), lo1 = min(kkey[0], kkey[1]);
        unsigned h2 = max(kkey[2], kkey[3]), lo2 = min(kkey[2], kkey[3]);
        unsigned m1 = max(h1, h2);
        unsigned m2 = max(min(h1, h2), max(lo1, lo2));
        int rowl = wv * 32 + rs * 16 + lq * 4 + rg2;
        dump[rowl * DSTR + l15 * 2 + 0] = m1;
        dump[rowl * DSTR + l15 * 2 + 1] = m2;
      }
    __syncthreads();

    // streaming top-8: 2 threads per row, 16 queue entries each
    {
      int srow = tid & 127;
      int qb = (tid >> 7) * 16;
      #pragma unroll
      for (int q = 0; q < 16; ++q) {
        unsigned cv = dump[srow * DSTR + qb + q];
        #pragma unroll
        for (int j = 0; j < 8; ++j) {
          unsigned hi = max(m[j], cv), lo = min(m[j], cv);
          m[j] = hi; cv = lo;
        }
      }
    }
    // loop-top barrier protects Bs against next tile's staging write
  }

  // merge the two partial top-8s per row, store
  __syncthreads();
  if (tid >= 128) {
    #pragma unroll
    for (int j = 0; j < 8; ++j) dump[(tid & 127) * DSTR + 16 + j] = m[j];
  }
  __syncthreads();
  if (tid < 128) {
    #pragma unroll
    for (int j = 0; j < 8; ++j) {
      unsigned cv = dump[tid * DSTR + 16 + j];
      #pragma unroll
      for (int jj = 0; jj < 8; ++jj) {
        unsigned hi = max(m[jj], cv), lo = min(m[jj], cv);
        m[jj] = hi; cv = lo;
      }
    }
    unsigned* o = candk + (size_t)(row0 + tid) * 32 + split * 8;
    #pragma unroll
    for (int j = 0; j < 8; ++j) o[j] = m[j];
  }
}

// ---------------------------------------------------------------------------
// refine v8 (unchanged): 4-at-a-time staging, pipelined gathers, atomic-free
// loss (per-row partials + 1-block finalize).
// ---------------------------------------------------------------------------
#define WSTR 516

__global__ __launch_bounds__(256, 3) void refine_mfma_kernel(
    const float* __restrict__ x, const float* __restrict__ emb,
    const float* __restrict__ den_w, const float* __restrict__ wnorm2,
    const unsigned* __restrict__ candk,
    float* __restrict__ out, double* __restrict__ lossparts) {
  __shared__ float xbuf[4][512];
  __shared__ float wbuf4[4][4 * WSTR];
  int w = threadIdx.x >> 6, l = threadIdx.x & 63;
  int row = blockIdx.x * 4 + w;

  const float* xr = x + (size_t)row * DIMS + l * 8;
  float4 x0 = *(const float4*)xr;
  float4 x1 = *(const float4*)(xr + 4);
  *(float4*)&xbuf[w][l * 8]     = x0;
  *(float4*)&xbuf[w][l * 8 + 4] = x1;
  __syncthreads();
  float Sx = np_pairwise_sumsq_512(xbuf[w], l);
  float denx = fmaxf(__fsqrt_rn(Sx), 1e-12f);
  float xn[8];
  xn[0] = __fdiv_rn(x0.x, denx); xn[1] = __fdiv_rn(x0.y, denx);
  xn[2] = __fdiv_rn(x0.z, denx); xn[3] = __fdiv_rn(x0.w, denx);
  xn[4] = __fdiv_rn(x1.x, denx); xn[5] = __fdiv_rn(x1.y, denx);
  xn[6] = __fdiv_rn(x1.z, denx); xn[7] = __fdiv_rn(x1.w, denx);
  __syncthreads();
  *(float4*)&xbuf[w][l * 8]     = float4{xn[0], xn[1], xn[2], xn[3]};
  *(float4*)&xbuf[w][l * 8 + 4] = float4{xn[4], xn[5], xn[6], xn[7]};
  __syncthreads();
  float xn2 = np_pairwise_sumsq_512(xbuf[w], l);

  // decode candidates: 4 splits x 8 keys, col-in-split is 11 bits
  unsigned val = 0u; int col = 0x7fffffff;
  if (l < 32) {
    unsigned key = candk[(size_t)row * 32 + l];
    val = key >> 12;
    col = (l >> 3) * SPLIT_COLS + (int)(key & 0xFFFu);
  }

  int k8[8];
  #pragma unroll
  for (int it = 0; it < 8; ++it) {
    unsigned mv = val; int mk = col;
    #pragma unroll
    for (int off = 1; off < 64; off <<= 1) {
      unsigned ov = (unsigned)__shfl_xor((int)mv, off, 64);
      int ok = __shfl_xor(mk, off, 64);
      bool take = (ov > mv) || (ov == mv && ok < mk);
      mv = take ? ov : mv; mk = take ? ok : mk;
    }
    k8[it] = mk;
    if (col == mk) val = 0u;
  }

  // ---- software-pipelined gather + 2 groups of 4 staged candidates ----
  float4 ga[4], gb[4];
  #pragma unroll
  for (int c = 0; c < 4; ++c) {
    const float* wr = emb + (size_t)k8[c] * DIMS + l * 8;
    ga[c] = *(const float4*)wr;
    gb[c] = *(const float4*)(wr + 4);
  }

  float d8[8];
  #pragma unroll
  for (int g = 0; g < 2; ++g) {
    // stage group g: fdiv (bit-identical) + LDS store
    #pragma unroll
    for (int c = 0; c < 4; ++c) {
      float dk = den_w[k8[g * 4 + c]];
      *(float4*)&wbuf4[w][c * WSTR + l * 8] =
          float4{__fdiv_rn(ga[c].x, dk), __fdiv_rn(ga[c].y, dk),
                 __fdiv_rn(ga[c].z, dk), __fdiv_rn(ga[c].w, dk)};
      *(float4*)&wbuf4[w][c * WSTR + l * 8 + 4] =
          float4{__fdiv_rn(gb[c].x, dk), __fdiv_rn(gb[c].y, dk),
                 __fdiv_rn(gb[c].z, dk), __fdiv_rn(gb[c].w, dk)};
    }
    // prefetch group 1 rows while group 0's chain runs (T14)
    if (g == 0) {
      #pragma unroll
      for (int c = 0; c < 4; ++c) {
        const float* wr = emb + (size_t)k8[4 + c] * DIMS + l * 8;
        ga[c] = *(const float4*)wr;
        gb[c] = *(const float4*)(wr + 4);
      }
    }
    __syncthreads();

    // exact sgemm-chain dots: lane computes candidate g*4 + (l&3)
    {
      int j = l & 3;
      const float* xp = xbuf[w];
      const float* wp = &wbuf4[w][j * WSTR];
      float t = 0.f;
      #pragma unroll 8
      for (int d = 0; d < 512; ++d) t = fmaf(xp[d], wp[d], t);
      #pragma unroll
      for (int c = 0; c < 4; ++c) {
        float dot = __shfl(t, c, 64);
        float s = __fadd_rn(xn2, wnorm2[k8[g * 4 + c]]);
        d8[g * 4 + c] = __fadd_rn(s, -(2.0f * dot));
      }
    }
    __syncthreads();   // wbuf4 consumed before group 1 overwrites
  }

  {
    float bd[3]; int bk[3];
    #pragma unroll
    for (int s = 0; s < 3; ++s) {
      float mv = INFINITY; int mk = 0x7fffffff;
      #pragma unroll
      for (int it = 0; it < 8; ++it) {
        bool take = (d8[it] < mv) || (d8[it] == mv && k8[it] < mk);
        mv = take ? d8[it] : mv; mk = take ? k8[it] : mk;
      }
      bd[s] = mv; bk[s] = mk;
      #pragma unroll
      for (int it = 0; it < 8; ++it)
        if (k8[it] == mk) d8[it] = INFINITY;
    }

    double i0 = 1.0 / (double)bd[0], i1 = 1.0 / (double)bd[1],
           i2 = 1.0 / (double)bd[2];
    double tot = (i0 + i1) + i2;
    double w0q = i0 / tot, w1q = i1 / tot, w2q = i2 / tot;

    if (l == 0) {
      float* oi = out + (size_t)N_ROWS * DIMS + 1 + (size_t)row * 3;
      oi[0] = (float)bk[0]; oi[1] = (float)bk[1]; oi[2] = (float)bk[2];
    }

    const float* e0 = emb + (size_t)bk[0] * DIMS + l * 8;
    const float* e1 = emb + (size_t)bk[1] * DIMS + l * 8;
    const float* e2 = emb + (size_t)bk[2] * DIMS + l * 8;
    float4 ea0 = *(const float4*)e0, eb0 = *(const float4*)(e0 + 4);
    float4 ea1 = *(const float4*)e1, eb1 = *(const float4*)(e1 + 4);
    float4 ea2 = *(const float4*)e2, eb2 = *(const float4*)(e2 + 4);
    double xs[8];
    xs[0] = x0.x; xs[1] = x0.y; xs[2] = x0.z; xs[3] = x0.w;
    xs[4] = x1.x; xs[5] = x1.y; xs[6] = x1.z; xs[7] = x1.w;
    double q[8];
    q[0] = w0q*(double)ea0.x + w1q*(double)ea1.x + w2q*(double)ea2.x;
    q[1] = w0q*(double)ea0.y + w1q*(double)ea1.y + w2q*(double)ea2.y;
    q[2] = w0q*(double)ea0.z + w1q*(double)ea1.z + w2q*(double)ea2.z;
    q[3] = w0q*(double)ea0.w + w1q*(double)ea1.w + w2q*(double)ea2.w;
    q[4] = w0q*(double)eb0.x + w1q*(double)eb1.x + w2q*(double)eb2.x;
    q[5] = w0q*(double)eb0.y + w1q*(double)eb1.y + w2q*(double)eb2.y;
    q[6] = w0q*(double)eb0.z + w1q*(double)eb1.z + w2q*(double)eb2.z;
    q[7] = w0q*(double)eb0.w + w1q*(double)eb1.w + w2q*(double)eb2.w;

    double lp = 0.0;
    float o[8];
    #pragma unroll
    for (int jj = 0; jj < 8; ++jj) {
      double diff = q[jj] - xs[jj];
      o[jj] = (float)(xs[jj] + diff);
      lp += diff * diff;
    }
    float* orow = out + (size_t)row * DIMS + l * 8;
    *(float4*)orow       = float4{o[0], o[1], o[2], o[3]};
    *(float4*)(orow + 4) = float4{o[4], o[5], o[6], o[7]};

    #pragma unroll
    for (int off = 1; off < 64; off <<= 1) lp += __shfl_xor(lp, off, 64);
    if (l == 0) lossparts[row] = lp;     // plain store; no atomic
  }
}

__global__ __launch_bounds__(256) void loss_finalize_kernel(
    const double* __restrict__ lossparts, float* __restrict__ out) {
  __shared__ double sred[4];
  int tid = threadIdx.x;
  double s = 0.0;
  for (int i = tid; i < N_ROWS; i += 256) s += lossparts[i];
  #pragma unroll
  for (int off = 1; off < 64; off <<= 1) s += __shfl_xor(s, off, 64);
  if ((tid & 63) == 0) sred[tid >> 6] = s;
  __syncthreads();
  if (tid == 0) {
    double m = (((sred[0] + sred[1]) + sred[2]) + sred[3]) / 16777216.0;
    out[(size_t)N_ROWS * DIMS] = (float)(m + 0.25 * m);
  }
}

// ---------------------------------------------------------------------------
// Workspace layout (~13.04 MB total):
//   wnorm2    [       0 ..   32768)  ||wn||^2 of normalized rows
//   den_w     [   32768 ..   65536)  fp32 norm denominator per codebook row
//   xninv     [   65536 ..  196608)  per-x-row inverse norm
//   wnh       [  196608 .. 8585216)  bf16 normalized codebook (8 MB)
//   candk     [ 8585216 .. 12779520) 32 packed keys/row (4 splits x top-8)
//   lossparts [12779520 .. 13041664) 32768 fp64 per-row partials (256 KB)
//   qctr      [13041664 .. 13042176) 4 queue counters @ 128B stride
// ---------------------------------------------------------------------------
extern "C" void kernel_launch(void* const* d_in, const int* in_sizes, int n_in,
                              void* d_out, int out_size, void* d_ws, size_t ws_size,
                              hipStream_t stream) {
  (void)in_sizes; (void)n_in; (void)out_size; (void)ws_size;
  const float* x   = (const float*)d_in[0];
  const float* emb = (const float*)d_in[1];
  float* out = (float*)d_out;
  char* ws = (char*)d_ws;

  float*          wnorm2    = (float*)(ws);
  float*          den_w     = (float*)(ws + 32768);
  float*          xninv     = (float*)(ws + 65536);
  unsigned short* wnh       = (unsigned short*)(ws + 196608);
  unsigned*       candk     = (unsigned*)(ws + 8585216);
  double*         lossparts = (double*)(ws + 12779520);
  unsigned*       qctr      = (unsigned*)(ws + 13041664);

  prep_w_np_kernel<<<K_CODES / 4, 256, 0, stream>>>(emb, den_w, wnorm2, wnh);
  prep_x_kernel<<<N_ROWS / 4, 256, 0, stream>>>(x, xninv);
  hipMemsetAsync(qctr, 0, 512, stream);
  mfma_topk_kernel<<<NROWGRP * NSPLIT, 256, 0, stream>>>(
      x, wnh, xninv, candk, qctr);
  refine_mfma_kernel<<<N_ROWS / 4, 256, 0, stream>>>(
      x, emb, den_w, wnorm2, candk, out, lossparts);
  loss_finalize_kernel<<<1, 256, 0, stream>>>(lossparts, out);
}